// Round 4
// baseline (646.240 us; speedup 1.0000x reference)
//
#include <hip/hip_runtime.h>
#include <stdint.h>

// FuncSelfAttention: b=4, s=256, E=256, H=8, d=32, p=16x16=256
// Round 4: all GEMMs NT with K-contiguous operands (vector b128 staging).
//   k_prep : W_qkv (split-major permuted) + W_out -> Wbf bf16 [1024][256]
//   k_tr   : seq f32 [bs][c][p] -> seqT bf16 [bs][p][c]   (LDS transpose)
//   k_qk   : Q,K = W[0:512] x seqT^T  -> Q,K [bh][s][dd][p]
//   k_v    : per (b,p): Wv x seqT-slice -> Vt [bh][dd*256+p][s]
//   k_scores: Q K^T, kc=8 K-split -> Sp f32 [kc][bh][q][ks]
//   k_softmax: sum partials, softmax -> P bf16
//   k_av   : P x Vt^T -> SA [bs][c][p]
//   k_out  : W_out x SA + b -> out f32 (transposed staging, batched loads)
//
// d_out: Qb 128 MiB | Kb 128 MiB (dead before k_out writes 64 MiB at base)
// d_ws : Vt 128 MiB | region R 128 MiB (seqT -> Sp -> SA, time-shared) |
//        Pb 4 MiB | Wbf 0.5 MiB   => 260.5 MiB peak (round-1-proven)

#define DI __device__ __forceinline__

typedef __attribute__((ext_vector_type(4))) float  f32x4;
typedef __attribute__((ext_vector_type(8))) short  s16x8;
typedef __attribute__((ext_vector_type(4))) short  s16x4;
typedef __attribute__((ext_vector_type(8))) __bf16 bf16x8;

DI unsigned short f2bf(float f) {
    unsigned int u = __builtin_bit_cast(unsigned int, f);
    u = (u + 0x7fffu + ((u >> 16) & 1u)) >> 16;
    return (unsigned short)u;
}
DI bf16x8 asbf(s16x8 v) { return __builtin_bit_cast(bf16x8, v); }
#define MFMA16(a, b, c) __builtin_amdgcn_mfma_f32_16x16x32_bf16((a), (b), (c), 0, 0, 0)

// ---- stage A [256 rows][64 k] bf16, one row per thread, chunk-XOR swizzle ---
DI void stage_a256(unsigned short* __restrict__ T,
                   const unsigned short* __restrict__ src, int stride, int tid) {
    const unsigned short* s = src + (size_t)tid * stride;
    int r7 = tid & 7;
#pragma unroll
    for (int ch = 0; ch < 8; ch++) {
        s16x8 v = *(const s16x8*)(s + ch * 8);
        *(s16x8*)&T[tid * 64 + ((ch ^ r7) << 3)] = v;
    }
}

// ---- stage [128 rows][64 k] bf16, two threads per row ----------------------
DI void stage_l128(unsigned short* __restrict__ T,
                   const unsigned short* __restrict__ src, int stride, int tid) {
    int row = tid >> 1, c4 = (tid & 1) * 4, r7 = row & 7;
    const unsigned short* s = src + (size_t)row * stride;
#pragma unroll
    for (int i = 0; i < 4; i++) {
        s16x8 v = *(const s16x8*)(s + (c4 + i) * 8);
        *(s16x8*)&T[row * 64 + (((c4 + i) ^ r7) << 3)] = v;
    }
}

// ---- transposed staging for k_out: batched loads, then writes --------------
DI void stage_tr16s(unsigned short* __restrict__ BT,
                    const unsigned short* __restrict__ src, int stride, int tid) {
    int p = tid & 127, cqh = tid >> 7, p7 = p & 7;
    unsigned short e[32];
#pragma unroll
    for (int i = 0; i < 8; i++) {
        int cb = (cqh + 2 * i) * 4;
        e[i * 4 + 0] = src[(size_t)(cb + 0) * stride + p];
        e[i * 4 + 1] = src[(size_t)(cb + 1) * stride + p];
        e[i * 4 + 2] = src[(size_t)(cb + 2) * stride + p];
        e[i * 4 + 3] = src[(size_t)(cb + 3) * stride + p];
    }
#pragma unroll
    for (int i = 0; i < 8; i++) {
        int cq = cqh + 2 * i;
        s16x4 v = {(short)e[i * 4 + 0], (short)e[i * 4 + 1],
                   (short)e[i * 4 + 2], (short)e[i * 4 + 3]};
        *(s16x4*)&BT[p * 64 + (((cq >> 1) ^ p7) << 3) + (cq & 1) * 4] = v;
    }
}

// ---- MFMA phase, wave tile 128x64 (mf=8, nf=4), BK=64 ----------------------
DI void mfma_84(const unsigned short* __restrict__ Al,
                const unsigned short* __restrict__ Bl,
                f32x4 acc[8][4], int wm, int wn, int lg, int lr) {
#pragma unroll
    for (int kk = 0; kk < 2; kk++) {
        int off = (((kk * 4 + lg) ^ (lr & 7)) << 3);
        s16x8 af[8];
#pragma unroll
        for (int m = 0; m < 8; m++)
            af[m] = *(const s16x8*)&Al[(wm + m * 16 + lr) * 64 + off];
        s16x8 bf[4];
#pragma unroll
        for (int n = 0; n < 4; n++)
            bf[n] = *(const s16x8*)&Bl[(wn + n * 16 + lr) * 64 + off];
#pragma unroll
        for (int n = 0; n < 4; n++) {
            bf16x8 bv = asbf(bf[n]);
#pragma unroll
            for (int m = 0; m < 8; m++)
                acc[m][n] = MFMA16(asbf(af[m]), bv, acc[m][n]);
        }
    }
}

// ===========================================================================
// k_prep: Wbf[1024][256]: rows 0..767 = W_qkv permuted (r = split*256+h*32+dd
// from source row h*96+split*32+dd), rows 768..1023 = W_out.
// ===========================================================================
__global__ __launch_bounds__(64) void k_prep(
    const float* __restrict__ Wqkv, const float* __restrict__ Wout,
    unsigned short* __restrict__ Wbf)
{
    int r = blockIdx.x, ln = threadIdx.x;
    const float* src;
    if (r < 768) {
        int split = r >> 8, hd = r & 255;
        src = Wqkv + (size_t)(((hd >> 5) * 96) + split * 32 + (hd & 31)) * 256;
    } else {
        src = Wout + (size_t)(r - 768) * 256;
    }
    f32x4 v = *(const f32x4*)(src + ln * 4);
    s16x4 h = {(short)f2bf(v.x), (short)f2bf(v.y), (short)f2bf(v.z), (short)f2bf(v.w)};
    *(s16x4*)&Wbf[(size_t)r * 256 + ln * 4] = h;
}

// ===========================================================================
// k_tr: seq f32 [bs][256 c][256 p] -> seqT bf16 [bs][256 p][256 c].
// grid 1024, block 256.  4 chunks of 64 c-rows via LDS [64][264].
// ===========================================================================
__global__ __launch_bounds__(256) void k_tr(
    const float* __restrict__ seq, unsigned short* __restrict__ seqT)
{
    const int bs = blockIdx.x, tid = threadIdx.x;
    __shared__ __align__(16) unsigned short T[64][264];
    const float* src = seq + (size_t)bs * 65536;
    unsigned short* dst = seqT + (size_t)bs * 65536;

    for (int co = 0; co < 256; co += 64) {
        {   // load [64 c][256 p] f32, convert, store rows to LDS
            int r = tid >> 2, p0 = (tid & 3) * 64;
            const float* s = src + (size_t)(co + r) * 256 + p0;
#pragma unroll
            for (int i = 0; i < 8; i++) {
                f32x4 a = *(const f32x4*)(s + i * 8);
                f32x4 b = *(const f32x4*)(s + i * 8 + 4);
                s16x8 h = {(short)f2bf(a.x), (short)f2bf(a.y), (short)f2bf(a.z),
                           (short)f2bf(a.w), (short)f2bf(b.x), (short)f2bf(b.y),
                           (short)f2bf(b.z), (short)f2bf(b.w)};
                *(s16x8*)&T[r][p0 + i * 8] = h;
            }
        }
        __syncthreads();
        {   // read columns (lanes = consecutive p -> conflict-free), write rows
            unsigned short e[64];
#pragma unroll
            for (int c = 0; c < 64; c++) e[c] = T[c][tid];
            unsigned short* d = dst + (size_t)tid * 256 + co;
#pragma unroll
            for (int j = 0; j < 8; j++) {
                s16x8 v = {(short)e[j * 8 + 0], (short)e[j * 8 + 1],
                           (short)e[j * 8 + 2], (short)e[j * 8 + 3],
                           (short)e[j * 8 + 4], (short)e[j * 8 + 5],
                           (short)e[j * 8 + 6], (short)e[j * 8 + 7]};
                *(s16x8*)(d + j * 8) = v;
            }
        }
        __syncthreads();
    }
}

// ===========================================================================
// k_qk: Q,K projection, NT.  grid 4096: x = bs*4 + mt*2 + nt.
// M=256 (split mt: 0=Q, 1=K), N=128 (p half), k=256 (c).
// ===========================================================================
__global__ __launch_bounds__(256, 2) void k_qk(
    const unsigned short* __restrict__ seqT, const unsigned short* __restrict__ Wbf,
    unsigned short* __restrict__ Qb, unsigned short* __restrict__ Kb)
{
    const int x = blockIdx.x;
    const int bs = x >> 2, mt = (x >> 1) & 1, nt = x & 1;
    const int b = bs >> 8, s = bs & 255;
    const int tid = threadIdx.x, ln = tid & 63, wv = tid >> 6;
    const int wm = (wv >> 1) * 128, wn = (wv & 1) * 64;
    const int lg = ln >> 4, lr = ln & 15;

    __shared__ __align__(16) unsigned short Al[256 * 64];
    __shared__ __align__(16) unsigned short Bt[128 * 64];

    f32x4 acc[8][4];
    const f32x4 z4 = {0.f, 0.f, 0.f, 0.f};
#pragma unroll
    for (int m = 0; m < 8; m++)
#pragma unroll
        for (int n = 0; n < 4; n++) acc[m][n] = z4;

    const unsigned short* Asrc = Wbf + (size_t)mt * 256 * 256;
    const unsigned short* Bsrc = seqT + (size_t)bs * 65536 + (size_t)(nt * 128) * 256;

    for (int k0 = 0; k0 < 256; k0 += 64) {
        stage_a256(Al, Asrc + k0, 256, tid);
        stage_l128(Bt, Bsrc + k0, 256, tid);
        __syncthreads();
        mfma_84(Al, Bt, acc, wm, wn, lg, lr);
        __syncthreads();
    }

    unsigned short* dst = mt ? Kb : Qb;
#pragma unroll
    for (int m = 0; m < 8; m++) {
#pragma unroll
        for (int rr = 0; rr < 4; rr++) {
            int o = wm + m * 16 + lg * 4 + rr;      // 0..255 = h*32+dd
            size_t base = ((size_t)((b * 8 + (o >> 5)) * 256 + s)) * 8192
                        + (size_t)(o & 31) * 256 + nt * 128 + wn + lr;
#pragma unroll
            for (int n = 0; n < 4; n++)
                dst[base + n * 16] = f2bf(acc[m][n][rr]);
        }
    }
}

// ===========================================================================
// k_v: V projection -> transposed Vt[bh][dd*256+p][s].  grid 2048:
// x = b*512 + p*2 + nt.  M=256 (h,dd), N=128 (s half), k=256 (c).
// B rows = seqT[(b,s)][p][:] (row stride 65536).
// ===========================================================================
__global__ __launch_bounds__(256, 2) void k_v(
    const unsigned short* __restrict__ seqT, const unsigned short* __restrict__ Wbf,
    unsigned short* __restrict__ Vt)
{
    const int x = blockIdx.x;
    const int b = x >> 9, p = (x >> 1) & 255, nt = x & 1;
    const int tid = threadIdx.x, ln = tid & 63, wv = tid >> 6;
    const int wm = (wv >> 1) * 128, wn = (wv & 1) * 64;
    const int lg = ln >> 4, lr = ln & 15;

    __shared__ __align__(16) unsigned short Al[256 * 64];
    __shared__ __align__(16) unsigned short Bt[128 * 64];

    f32x4 acc[8][4];
    const f32x4 z4 = {0.f, 0.f, 0.f, 0.f};
#pragma unroll
    for (int m = 0; m < 8; m++)
#pragma unroll
        for (int n = 0; n < 4; n++) acc[m][n] = z4;

    const unsigned short* Asrc = Wbf + (size_t)512 * 256;
    const unsigned short* Bsrc = seqT + ((size_t)(b * 256 + nt * 128)) * 65536
                               + (size_t)p * 256;

    for (int k0 = 0; k0 < 256; k0 += 64) {
        stage_a256(Al, Asrc + k0, 256, tid);
        stage_l128(Bt, Bsrc + k0, 65536, tid);
        __syncthreads();
        mfma_84(Al, Bt, acc, wm, wn, lg, lr);
        __syncthreads();
    }

#pragma unroll
    for (int m = 0; m < 8; m++) {
#pragma unroll
        for (int rr = 0; rr < 4; rr++) {
            int o = wm + m * 16 + lg * 4 + rr;      // h*32+dd
            size_t base = ((size_t)(b * 8 + (o >> 5)) * 8192
                         + (size_t)(o & 31) * 256 + p) * 256 + nt * 128 + wn + lr;
#pragma unroll
            for (int n = 0; n < 4; n++)
                Vt[base + n * 16] = f2bf(acc[m][n][rr]);
        }
    }
}

// ===========================================================================
// k_scores: Q K^T partials, NT.  grid (16, 32): x = st*8 + kc, y = bh.
// M=256 (all q), N=128 (ks half), K-slice 1024 per kc.
// ===========================================================================
__global__ __launch_bounds__(256, 2) void k_scores(
    const unsigned short* __restrict__ Qb, const unsigned short* __restrict__ Kb,
    float* __restrict__ Sp)
{
    const int bh = blockIdx.y;
    const int st = blockIdx.x >> 3, kc = blockIdx.x & 7;
    const int tid = threadIdx.x, ln = tid & 63, wv = tid >> 6;
    const int wm = (wv >> 1) * 128, wn = (wv & 1) * 64;
    const int lg = ln >> 4, lr = ln & 15;

    __shared__ __align__(16) unsigned short Al[256 * 64];
    __shared__ __align__(16) unsigned short Bt[128 * 64];

    f32x4 acc[8][4];
    const f32x4 z4 = {0.f, 0.f, 0.f, 0.f};
#pragma unroll
    for (int m = 0; m < 8; m++)
#pragma unroll
        for (int n = 0; n < 4; n++) acc[m][n] = z4;

    const unsigned short* Asrc = Qb + (size_t)(bh * 256) * 8192 + kc * 1024;
    const unsigned short* Bsrc = Kb + (size_t)(bh * 256 + st * 128) * 8192 + kc * 1024;

    for (int t = 0; t < 16; t++) {
        stage_a256(Al, Asrc + t * 64, 8192, tid);
        stage_l128(Bt, Bsrc + t * 64, 8192, tid);
        __syncthreads();
        mfma_84(Al, Bt, acc, wm, wn, lg, lr);
        __syncthreads();
    }

    float* dst = Sp + (size_t)kc * 2097152 + (size_t)(bh * 256) * 256 + st * 128;
#pragma unroll
    for (int m = 0; m < 8; m++) {
#pragma unroll
        for (int rr = 0; rr < 4; rr++) {
            float* d = dst + (size_t)(wm + m * 16 + lg * 4 + rr) * 256 + wn + lr;
#pragma unroll
            for (int n = 0; n < 4; n++)
                d[n * 16] = acc[m][n][rr];
        }
    }
}

// ===========================================================================
// k_softmax: sum 8 partials, scale, softmax -> P bf16.  grid 2048 x 256.
// ===========================================================================
__global__ __launch_bounds__(256) void k_softmax(
    const float* __restrict__ Sp, unsigned short* __restrict__ Pb)
{
    const int tid = threadIdx.x, ln = tid & 63;
    const int row = blockIdx.x * 4 + (tid >> 6);
    const float scale = 0.011048543456039806f;  // 1/sqrt(32*256)

    const float* p0 = Sp + (size_t)row * 256 + ln * 4;
    f32x4 v = *(const f32x4*)p0;
#pragma unroll
    for (int k = 1; k < 8; k++)
        v += *(const f32x4*)(p0 + (size_t)k * 2097152);
    v *= scale;

    float m = fmaxf(fmaxf(v.x, v.y), fmaxf(v.z, v.w));
#pragma unroll
    for (int off = 32; off; off >>= 1) m = fmaxf(m, __shfl_xor(m, off));
    float e0 = __expf(v.x - m), e1 = __expf(v.y - m);
    float e2 = __expf(v.z - m), e3 = __expf(v.w - m);
    float sum = e0 + e1 + e2 + e3;
#pragma unroll
    for (int off = 32; off; off >>= 1) sum += __shfl_xor(sum, off);
    float inv = 1.f / sum;
    s16x4 p = {(short)f2bf(e0 * inv), (short)f2bf(e1 * inv),
               (short)f2bf(e2 * inv), (short)f2bf(e3 * inv)};
    *(s16x4*)(Pb + (size_t)row * 256 + ln * 4) = p;
}

// ===========================================================================
// k_av: SA = P V, NT vs Vt.  grid (64, 32): x = ft, y = bh.
// M=256 (all q), N=128 (f-slice), k=256 (ks).
// ===========================================================================
__global__ __launch_bounds__(256, 2) void k_av(
    const unsigned short* __restrict__ Pb, const unsigned short* __restrict__ Vt,
    unsigned short* __restrict__ SAb)
{
    const int ft = blockIdx.x, bh = blockIdx.y;
    const int b = bh >> 3, h = bh & 7;
    const int tid = threadIdx.x, ln = tid & 63, wv = tid >> 6;
    const int wm = (wv >> 1) * 128, wn = (wv & 1) * 64;
    const int lg = ln >> 4, lr = ln & 15;

    __shared__ __align__(16) unsigned short Al[256 * 64];
    __shared__ __align__(16) unsigned short Bt[128 * 64];

    f32x4 acc[8][4];
    const f32x4 z4 = {0.f, 0.f, 0.f, 0.f};
#pragma unroll
    for (int m = 0; m < 8; m++)
#pragma unroll
        for (int n = 0; n < 4; n++) acc[m][n] = z4;

    const unsigned short* Asrc = Pb + (size_t)bh * 65536;
    const unsigned short* Bsrc = Vt + (size_t)bh * 2097152 + (size_t)(ft * 128) * 256;

    for (int k0 = 0; k0 < 256; k0 += 64) {
        stage_a256(Al, Asrc + k0, 256, tid);
        stage_l128(Bt, Bsrc + k0, 256, tid);
        __syncthreads();
        mfma_84(Al, Bt, acc, wm, wn, lg, lr);
        __syncthreads();
    }

    // SA[bs][c][p]: addr = (b*256+q)*65536 + h*8192 + f,  f = ft*128 + col
#pragma unroll
    for (int m = 0; m < 8; m++) {
#pragma unroll
        for (int rr = 0; rr < 4; rr++) {
            int q = wm + m * 16 + lg * 4 + rr;
            size_t base = (size_t)(b * 256 + q) * 65536 + h * 8192
                        + ft * 128 + wn + lr;
#pragma unroll
            for (int n = 0; n < 4; n++)
                SAb[base + n * 16] = f2bf(acc[m][n][rr]);
        }
    }
}

// ===========================================================================
// k_out: out = W_out SA + b (NN, batched transposed staging).
// grid (2, 1024): x = nt, y = bs.  M=256 (o), N=128 (p), k=256 (c).
// ===========================================================================
__global__ __launch_bounds__(256, 2) void k_out(
    const unsigned short* __restrict__ SAb, const unsigned short* __restrict__ Wbf,
    const float* __restrict__ bias, float* __restrict__ out)
{
    const int nt = blockIdx.x, bs = blockIdx.y;
    const int tid = threadIdx.x, ln = tid & 63, wv = tid >> 6;
    const int wm = (wv >> 1) * 128, wn = (wv & 1) * 64;
    const int lg = ln >> 4, lr = ln & 15;

    __shared__ __align__(16) unsigned short Al[256 * 64];
    __shared__ __align__(16) unsigned short Bt[128 * 64];

    f32x4 acc[8][4];
    const f32x4 z4 = {0.f, 0.f, 0.f, 0.f};
#pragma unroll
    for (int m = 0; m < 8; m++)
#pragma unroll
        for (int n = 0; n < 4; n++) acc[m][n] = z4;

    const unsigned short* Asrc = Wbf + (size_t)768 * 256;
    const unsigned short* Bsrc = SAb + (size_t)bs * 65536 + nt * 128;

    for (int k0 = 0; k0 < 256; k0 += 64) {
        stage_a256(Al, Asrc + k0, 256, tid);
        stage_tr16s(Bt, Bsrc + (size_t)k0 * 256, 256, tid);
        __syncthreads();
        mfma_84(Al, Bt, acc, wm, wn, lg, lr);
        __syncthreads();
    }

#pragma unroll
    for (int m = 0; m < 8; m++) {
#pragma unroll
        for (int rr = 0; rr < 4; rr++) {
            int o = wm + m * 16 + lg * 4 + rr;
            float bo = bias[o];
            float* d = out + ((size_t)bs * 256 + o) * 256 + nt * 128 + wn + lr;
#pragma unroll
            for (int n = 0; n < 4; n++)
                d[n * 16] = acc[m][n][rr] + bo;
        }
    }
}

// ---------------------------------------------------------------------------
extern "C" void kernel_launch(void* const* d_in, const int* in_sizes, int n_in,
                              void* d_out, int out_size, void* d_ws, size_t ws_size,
                              hipStream_t stream)
{
    const float* seq  = (const float*)d_in[0];
    const float* Wqkv = (const float*)d_in[1];
    const float* Wout = (const float*)d_in[2];
    const float* bout = (const float*)d_in[3];

    // d_out: Q | K (dead before k_out writes the final 64 MiB at the base)
    unsigned short* Qb = (unsigned short*)d_out;
    unsigned short* Kb = Qb + 67108864;

    // d_ws: Vt | region R (seqT -> Sp -> SA) | Pb | Wbf
    unsigned short* Vt   = (unsigned short*)d_ws;
    unsigned short* seqT = Vt + 67108864;
    float*          Sp   = (float*)seqT;
    unsigned short* SAb  = seqT;
    unsigned short* Pb   = (unsigned short*)d_ws + 134217728;
    unsigned short* Wbf  = Pb + 2097152;

    float* out = (float*)d_out;

    k_prep<<<dim3(1024), dim3(64), 0, stream>>>(Wqkv, Wout, Wbf);
    k_tr<<<dim3(1024), dim3(256), 0, stream>>>(seq, seqT);
    k_qk<<<dim3(4096), dim3(256), 0, stream>>>(seqT, Wbf, Qb, Kb);
    k_v<<<dim3(2048), dim3(256), 0, stream>>>(seqT, Wbf, Vt);
    k_scores<<<dim3(16, 32), dim3(256), 0, stream>>>(Qb, Kb, Sp);
    k_softmax<<<dim3(2048), dim3(256), 0, stream>>>(Sp, Pb);
    k_av<<<dim3(64, 32), dim3(256), 0, stream>>>(Pb, Vt, SAb);
    k_out<<<dim3(2, 1024), dim3(256), 0, stream>>>(SAb, Wbf, bout, out);
}